// Round 5
// baseline (20913.510 us; speedup 1.0000x reference)
//
#include <hip/hip_runtime.h>
#include <stdint.h>

#define TT 16384
#define DH 512
#define KK 128
#define SENT 0xAAAAAAAAu
#define CROWS 32
#define NCHUNK (TT / CROWS)   // 512
#define NPROJ 56
#define RSLOT 16

// LDS-only barrier (round-4: proven neutral vs __syncthreads, semantically
// sufficient — all in-block cross-thread data is LDS; cross-block data uses
// per-word parity/sentinel protocols that need no drain ordering).
#define BARRIER_LDS() do { \
    asm volatile("s_waitcnt lgkmcnt(0)" ::: "memory"); \
    __builtin_amdgcn_s_barrier(); \
} while (0)

// Small cross-block state lives in device globals (ws budget stays at the
// proven 2*TT*DH floats). Re-initialized by init_kernel every launch.
__device__ uint32_t g_ring[2][RSLOT][DH];   // parity-tagged h exchange rings
__device__ uint32_t g_flagXp[2][NCHUNK];    // Xp chunk-ready flags (1 = ready)

static __device__ __forceinline__ uint32_t aload(const uint32_t* p) {
    return __hip_atomic_load(p, __ATOMIC_RELAXED, __HIP_MEMORY_SCOPE_AGENT);
}
static __device__ __forceinline__ void astore(uint32_t* p, uint32_t v) {
    __hip_atomic_store(p, v, __ATOMIC_RELAXED, __HIP_MEMORY_SCOPE_AGENT);
}
static __device__ __forceinline__ float aloadf(const float* p) {
    return __uint_as_float(aload((const uint32_t*)p));
}

// 4-deep pipelined MALL poll (wave-level, exec must be all-ones).
// Keeps 4 outstanding sc0+sc1 loads to p; checks the oldest each pass
// (s_waitcnt vmcnt(3)) -> sampling period ~RTT/4 instead of RTT.
// Exits when ALL lanes see bit31 == expected>>31 (value returned), or after
// 16 passes (returns a mismatching value; caller falls back to the proven
// per-thread agent-atomic loop — correctness never depends on the sc bits).
// Register-rotation safety: at each detect point PDk, the in-flight loads
// target the three OTHER temp regs, never the one holding the detected value,
// and the result is moved into %0 which no load ever targets.
static __device__ __forceinline__ uint32_t poll4(const uint32_t* p, uint32_t expected) {
    uint32_t res, t0, t1, t2, t3, cnt;
    asm volatile(
        "s_mov_b32 %5, 16\n\t"
        "global_load_dword %1, %6, off sc0 sc1\n\t"
        "global_load_dword %2, %6, off sc0 sc1\n\t"
        "global_load_dword %3, %6, off sc0 sc1\n\t"
        "global_load_dword %4, %6, off sc0 sc1\n\t"
        "PLOOP%=:\n\t"
        "s_waitcnt vmcnt(3)\n\t"
        "v_xor_b32 %0, %7, %1\n\t"
        "v_cmp_gt_i32 vcc, 0, %0\n\t"
        "s_cbranch_vccz PD0%=\n\t"
        "global_load_dword %1, %6, off sc0 sc1\n\t"
        "s_waitcnt vmcnt(3)\n\t"
        "v_xor_b32 %0, %7, %2\n\t"
        "v_cmp_gt_i32 vcc, 0, %0\n\t"
        "s_cbranch_vccz PD1%=\n\t"
        "global_load_dword %2, %6, off sc0 sc1\n\t"
        "s_waitcnt vmcnt(3)\n\t"
        "v_xor_b32 %0, %7, %3\n\t"
        "v_cmp_gt_i32 vcc, 0, %0\n\t"
        "s_cbranch_vccz PD2%=\n\t"
        "global_load_dword %3, %6, off sc0 sc1\n\t"
        "s_waitcnt vmcnt(3)\n\t"
        "v_xor_b32 %0, %7, %4\n\t"
        "v_cmp_gt_i32 vcc, 0, %0\n\t"
        "s_cbranch_vccz PD3%=\n\t"
        "global_load_dword %4, %6, off sc0 sc1\n\t"
        "s_sub_u32 %5, %5, 1\n\t"
        "s_cmp_lg_u32 %5, 0\n\t"
        "s_cbranch_scc1 PLOOP%=\n\t"
        "s_waitcnt vmcnt(0)\n\t"          // exhausted: drain, hand back slot 3
        "v_mov_b32 %0, %4\n\t"
        "s_branch PFIN%=\n\t"
        "PD0%=: v_mov_b32 %0, %1\n\t"
        "s_branch PFIN%=\n\t"
        "PD1%=: v_mov_b32 %0, %2\n\t"
        "s_branch PFIN%=\n\t"
        "PD2%=: v_mov_b32 %0, %3\n\t"
        "s_branch PFIN%=\n\t"
        "PD3%=: v_mov_b32 %0, %4\n\t"
        "PFIN%=:\n\t"
        "s_waitcnt vmcnt(0)\n\t"          // retire leftovers into dead temps
        : "=&v"(res), "=&v"(t0), "=&v"(t1), "=&v"(t2), "=&v"(t3), "=&s"(cnt)
        : "v"(p), "v"(expected)
        : "vcc", "scc", "memory");
    return res;
}

__global__ void init_kernel() {
    const int tid = threadIdx.x;
    uint32_t* r = &g_ring[0][0][0];
    for (int i = tid; i < 2 * RSLOT * DH; i += 1024) r[i] = SENT;  // sign bit 1
    uint32_t* f = &g_flagXp[0][0];
    for (int i = tid; i < 2 * NCHUNK; i += 1024) f[i] = SENT;      // != 1
}

// ---------------- projector: 32-row chunk GEMM  dst = src @ W  ----------------
// srcMode 0: plain loads (X, pre-written).  srcMode 1: per-word sentinel poll
// (H0, written live by scan-0; in-place overwrite is safe: sole consumer is us,
// and the chunk is fully staged to LDS before any store).
static __device__ void proj_chunk(const float* __restrict__ W,
                                  const float* __restrict__ src, int srcMode,
                                  float* __restrict__ dst, uint32_t* flag, int t0,
                                  float* inT /* [DH][36] */, float* wt /* [32][516] */)
{
    const int tid = threadIdx.x;
    // stage input chunk transposed: inT[k][row]
    #pragma unroll
    for (int i = 0; i < 16; ++i) {
        int idx = tid + 1024 * i;            // 0..16383
        int row = idx >> 9;
        int col = idx & 511;
        float v;
        if (srcMode == 0) {
            v = src[(size_t)t0 * DH + idx];
        } else {
            const uint32_t* p = (const uint32_t*)src + (size_t)t0 * DH + idx;
            uint32_t u;
            while ((u = aload(p)) == SENT) __builtin_amdgcn_s_sleep(1);
            v = __uint_as_float(u);
        }
        inT[col * 36 + row] = v;
    }
    __syncthreads();

    const int rg = (tid >> 7) & 7;   // row group: rows 4rg..4rg+3
    const int cg = tid & 127;        // col group: cols 4cg..4cg+3
    float acc[4][4] = {{0.f}};

    for (int kt = 0; kt < 16; ++kt) {
        const int k0 = kt * 32;
        #pragma unroll
        for (int i = 0; i < 4; ++i) {                  // stage 32x512 W tile
            int f4 = tid + 1024 * i;                   // 0..4095 float4s
            int wr = f4 >> 7;
            int wc = (f4 & 127) << 2;
            *(float4*)&wt[wr * 516 + wc] =
                *(const float4*)&W[(size_t)(k0 + wr) * DH + wc];
        }
        __syncthreads();
        #pragma unroll 8
        for (int kk = 0; kk < 32; ++kk) {
            float4 a = *(const float4*)&inT[(k0 + kk) * 36 + (rg << 2)];
            float4 w = *(const float4*)&wt[kk * 516 + (cg << 2)];
            acc[0][0] += a.x * w.x; acc[0][1] += a.x * w.y; acc[0][2] += a.x * w.z; acc[0][3] += a.x * w.w;
            acc[1][0] += a.y * w.x; acc[1][1] += a.y * w.y; acc[1][2] += a.y * w.z; acc[1][3] += a.y * w.w;
            acc[2][0] += a.z * w.x; acc[2][1] += a.z * w.y; acc[2][2] += a.z * w.z; acc[2][3] += a.z * w.w;
            acc[3][0] += a.w * w.x; acc[3][1] += a.w * w.y; acc[3][2] += a.w * w.z; acc[3][3] += a.w * w.w;
        }
        __syncthreads();
    }
    #pragma unroll
    for (int i = 0; i < 4; ++i)
        #pragma unroll
        for (int j = 0; j < 4; ++j)
            astore((uint32_t*)&dst[(size_t)(t0 + (rg << 2) + i) * DH + (cg << 2) + j],
                   __float_as_uint(acc[i][j]));
    __threadfence();
    __syncthreads();
    if (tid == 0)
        __hip_atomic_store(flag, 1u, __ATOMIC_RELEASE, __HIP_MEMORY_SCOPE_AGENT);
}

// ---------------- fused persistent kernel ----------------
// grid = 64 x 1024.  Blocks with (b<32 && b%8<2): scan role, layer=b%8, slice=b>>3
// (b%8 swizzle: layer-0 scan blocks land on one XCD if dispatch is round-robin —
// perf heuristic only).  All other blocks: projectors for Xp0/Xp1.
// Scan structure = proven round-0 baseline + round-4 LDS barriers (neutral).
// Round-5 change: 4-deep pipelined polling (poll4) — sampling period RTT/4.
__global__ __launch_bounds__(1024, 1)
void fused(const float* __restrict__ X,
           const float* __restrict__ Wx0, const float* __restrict__ Wh0,
           const float* __restrict__ bh0, const float* __restrict__ h00,
           const float* __restrict__ Wx1, const float* __restrict__ Wh1,
           const float* __restrict__ bh1, const float* __restrict__ h01,
           float* H0r, float* H1r)
{
    __shared__ __align__(16) float s_hbuf[DH];
    __shared__ float s_part[8][128];
    __shared__ __align__(16) float s_inT[DH * 36];    // 73728 B
    __shared__ __align__(16) float s_wt[32 * 516];    // 66048 B

    const int bIdx = blockIdx.x;
    const int m8 = bIdx & 7;
    const int tid = threadIdx.x;

    if (bIdx < 32 && m8 < 2) {
        // ================= scan role =================
        const int L = m8;
        const int b = bIdx >> 3;          // slice 0..3, owns cols [128b,128b+128)
        const int c = tid >> 7;           // input chunk 0..7 (64 inputs)
        const int o = tid & 127;
        const int og = (b << 7) + o;

        const float* Wh  = L ? Wh1 : Wh0;
        const float* bhv = L ? bh1 : bh0;
        const float* h0v = L ? h01 : h00;
        float* Hful      = L ? H1r : H0r;
        const float* Xp  = L ? H0r : H1r;   // Xp1 overlays H0, Xp0 overlays H1
        uint32_t* ring         = &g_ring[L][0][0];
        uint32_t* flagXp       = &g_flagXp[L][0];

        float wh[64];
        #pragma unroll
        for (int j = 0; j < 64; ++j)
            wh[j] = Wh[(size_t)((c << 6) + j) * DH + og];
        const float bias = bhv[og];

        // pollers: 384 threads outside the self range (6 FULL waves — exec
        // all-ones inside poll4), one remote col each
        const int ptid = (tid + 1024 - ((b << 8) + 256)) & 1023;
        const bool isPoll = ptid < 384;
        const int pcol = (ptid < (b << 7)) ? ptid : ptid + 128;
        const bool isSelf = (c >> 1) == b;
        const bool isRed = tid < 128;     // reducer threads, o == tid

        if (tid < DH) s_hbuf[tid] = h0v[tid];

        float xp_next = 0.f;
        int curCh = -1;
        if (isRed) {
            while (__hip_atomic_load(&flagXp[0], __ATOMIC_ACQUIRE,
                                     __HIP_MEMORY_SCOPE_AGENT) != 1u)
                __builtin_amdgcn_s_sleep(1);
            curCh = 0;
            xp_next = aloadf(&Xp[og]);
        }
        __syncthreads();

        for (int t = 0; t < TT; ++t) {
            if (t > 0 && isPoll) {
                const uint32_t par = (uint32_t)((t - 1) >> 4) & 1u;
                const uint32_t expected = par << 31;
                const uint32_t* p = &ring[(((t - 1) & 15) << 9) + pcol];
                uint32_t v = poll4(p, expected);
                if ((int32_t)(v ^ expected) < 0) {
                    // fallback: proven agent-atomic loop (extreme skew, or
                    // sc-bit mapping mismatch — correctness never at risk)
                    do { v = aload(p); } while ((v >> 31) != par);
                }
                s_hbuf[pcol] = __uint_as_float(v & 0x7fffffffu);
            }
            float acc = 0.f;
            if (isSelf | (t == 0)) {       // phase 1: overlaps the round trip
                const float4* h4 = (const float4*)&s_hbuf[c << 6];
                #pragma unroll
                for (int j4 = 0; j4 < 16; ++j4) {
                    float4 hv = h4[j4];
                    acc += wh[4*j4+0]*hv.x + wh[4*j4+1]*hv.y
                         + wh[4*j4+2]*hv.z + wh[4*j4+3]*hv.w;
                }
                s_part[c][o] = acc;
            }
            BARRIER_LDS();                 // remote h staged
            if (!(isSelf | (t == 0))) {    // phase 2: remote-dependent FMAs
                const float4* h4 = (const float4*)&s_hbuf[c << 6];
                #pragma unroll
                for (int j4 = 0; j4 < 16; ++j4) {
                    float4 hv = h4[j4];
                    acc += wh[4*j4+0]*hv.x + wh[4*j4+1]*hv.y
                         + wh[4*j4+2]*hv.z + wh[4*j4+3]*hv.w;
                }
                s_part[c][o] = acc;
            }
            BARRIER_LDS();                 // partials ready
            if (isRed) {
                float v = bias + xp_next;
                #pragma unroll
                for (int cc = 0; cc < 8; ++cc) v += s_part[cc][o];
                v = fmaxf(v, 0.f);
                const uint32_t hb = __float_as_uint(v);
                // ring store FIRST: other blocks' pollers depend on it
                astore(&ring[((t & 15) << 9) + og],
                       hb | (((uint32_t)(t >> 4) & 1u) << 31));
                astore((uint32_t*)Hful + (size_t)t * DH + og, hb);
                s_hbuf[og] = v;
                if (t + 1 < TT) {          // prefetch next xp (off critical path)
                    const int ch = (t + 1) >> 5;
                    if (ch != curCh) {
                        while (__hip_atomic_load(&flagXp[ch], __ATOMIC_ACQUIRE,
                                                 __HIP_MEMORY_SCOPE_AGENT) != 1u) {}
                        curCh = ch;
                    }
                    xp_next = aloadf(&Xp[(size_t)(t + 1) * DH + og]);
                }
            }
            BARRIER_LDS();                 // hbuf self-slice ready for next step
        }
    } else {
        // ================= projector role =================
        const int pi = (bIdx < 32) ? (((bIdx >> 3) * 6) + (m8 - 2))
                                   : (24 + (bIdx - 32));      // 0..55
        for (int cc = pi; cc < NCHUNK; cc += NPROJ) {
            proj_chunk(Wx0, X,   0, H1r /*Xp0*/, &g_flagXp[0][cc], cc * CROWS, s_inT, s_wt);
            proj_chunk(Wx1, H0r, 1, H0r /*Xp1*/, &g_flagXp[1][cc], cc * CROWS, s_inT, s_wt);
        }
    }
}

// out[t][k] = dot(H1[t], W_log[k]) + b_log[k].  Block = 8 timesteps x 128 k.
__global__ __launch_bounds__(128, 1)
void logits_kernel(const float* __restrict__ H1, const float* __restrict__ Wl,
                   const float* __restrict__ bl, float* __restrict__ out)
{
    const int t0 = blockIdx.x * 8;
    const int k = threadIdx.x;

    __shared__ __align__(16) float hs[8 * DH];
    for (int idx = k; idx < 8 * DH / 4; idx += 128)
        ((float4*)hs)[idx] = ((const float4*)&H1[(size_t)t0 * DH])[idx];
    __syncthreads();

    float acc[8];
    const float bk = bl[k];
    #pragma unroll
    for (int r = 0; r < 8; ++r) acc[r] = bk;

    const float4* w4 = (const float4*)&Wl[(size_t)k * DH];
    for (int j = 0; j < DH / 4; ++j) {
        float4 w = w4[j];
        #pragma unroll
        for (int r = 0; r < 8; ++r) {
            float4 h = ((const float4*)&hs[r * DH])[j];
            acc[r] += w.x * h.x + w.y * h.y + w.z * h.z + w.w * h.w;
        }
    }
    #pragma unroll
    for (int r = 0; r < 8; ++r) out[(size_t)(t0 + r) * KK + k] = acc[r];
}

extern "C" void kernel_launch(void* const* d_in, const int* in_sizes, int n_in,
                              void* d_out, int out_size, void* d_ws, size_t ws_size,
                              hipStream_t stream)
{
    const float* X   = (const float*)d_in[0];
    const float* Wx0 = (const float*)d_in[1];
    const float* Wh0 = (const float*)d_in[2];
    const float* bh0 = (const float*)d_in[3];
    const float* h00 = (const float*)d_in[4];
    const float* Wx1 = (const float*)d_in[5];
    const float* Wh1 = (const float*)d_in[6];
    const float* bh1 = (const float*)d_in[7];
    const float* h01 = (const float*)d_in[8];
    const float* Wl  = (const float*)d_in[9];
    const float* bl  = (const float*)d_in[10];
    float* out = (float*)d_out;

    float* H0r = (float*)d_ws;                  // H0, later overlaid by Xp1
    float* H1r = H0r + (size_t)TT * DH;         // Xp0 first, then H1

    // H0 region must start at sentinel (harness poisons d_ws; this is defensive)
    hipMemsetAsync(d_ws, 0xAA, (size_t)TT * DH * sizeof(float), stream);
    hipLaunchKernelGGL(init_kernel, dim3(1), dim3(1024), 0, stream);
    hipLaunchKernelGGL(fused, dim3(64), dim3(1024), 0, stream,
                       X, Wx0, Wh0, bh0, h00, Wx1, Wh1, bh1, h01, H0r, H1r);
    hipLaunchKernelGGL(logits_kernel, dim3(TT / 8), dim3(128), 0, stream,
                       H1r, Wl, bl, out);
}

// Round 7
// 19991.443 us; speedup vs baseline: 1.0461x; 1.0461x over previous
//
#include <hip/hip_runtime.h>
#include <stdint.h>

#define TT 16384
#define DH 512
#define KK 128
#define SENT 0xAAAAAAAAu
#define CROWS 32
#define NCHUNK (TT / CROWS)   // 512
#define NPROJ 56
#define RSLOT 16

// LDS-only barrier (round-4: proven neutral vs __syncthreads, semantically
// sufficient — all in-block cross-thread data is LDS; cross-block data uses
// per-word parity/sentinel protocols that need no drain ordering).
#define BARRIER_LDS() do { \
    asm volatile("s_waitcnt lgkmcnt(0)" ::: "memory"); \
    __builtin_amdgcn_s_barrier(); \
} while (0)

// Small cross-block state lives in device globals (ws budget stays at the
// proven 2*TT*DH floats). Re-initialized by init_kernel every launch.
__device__ uint32_t g_ringF[2][RSLOT][DH];  // FAST ring: same-XCD L2 (sc0)
__device__ uint32_t g_ringM[2][RSLOT][DH];  // MIRROR ring: agent scope (proven)
__device__ uint32_t g_flagXp[2][NCHUNK];    // Xp chunk-ready flags (1 = ready)
__device__ uint32_t g_cnt[8];               // per-XCD registration counters
__device__ uint32_t g_total;                // total registered blocks
__device__ uint32_t g_members[8][64];       // blockIdx by (xcd, slot)

static __device__ __forceinline__ uint32_t aload(const uint32_t* p) {
    return __hip_atomic_load(p, __ATOMIC_RELAXED, __HIP_MEMORY_SCOPE_AGENT);
}
static __device__ __forceinline__ void astore(uint32_t* p, uint32_t v) {
    __hip_atomic_store(p, v, __ATOMIC_RELAXED, __HIP_MEMORY_SCOPE_AGENT);
}
static __device__ __forceinline__ float aloadf(const float* p) {
    return __uint_as_float(aload((const uint32_t*)p));
}

// Same-XCD L2 path: sc0 = L1-bypass, coherent at the XCD's shared L2.
// (Flag syntax proven to assemble+run by round-5's poll4.)  Used ONLY on the
// fast ring; every consumer has a bounded-retry escape to the agent mirror,
// so correctness NEVER depends on sc0 semantics or block placement.
static __device__ __forceinline__ uint32_t l2load(const uint32_t* p) {
    uint32_t v;
    asm volatile("global_load_dword %0, %1, off sc0\n\ts_waitcnt vmcnt(0)"
                 : "=&v"(v) : "v"(p) : "memory");
    return v;
}
static __device__ __forceinline__ void l2store(uint32_t* p, uint32_t v) {
    asm volatile("global_store_dword %0, %1, off sc0" :: "v"(p), "v"(v) : "memory");
}

__global__ void init_kernel() {
    const int tid = threadIdx.x;
    uint32_t* rf = &g_ringF[0][0][0];
    for (int i = tid; i < 2 * RSLOT * DH; i += 1024) rf[i] = SENT;  // sign bit 1
    uint32_t* rm = &g_ringM[0][0][0];
    for (int i = tid; i < 2 * RSLOT * DH; i += 1024) rm[i] = SENT;
    uint32_t* f = &g_flagXp[0][0];
    for (int i = tid; i < 2 * NCHUNK; i += 1024) f[i] = SENT;      // != 1
    uint32_t* m = &g_members[0][0];
    for (int i = tid; i < 8 * 64; i += 1024) m[i] = 0xFFFFFFFFu;
    if (tid < 8) g_cnt[tid] = 0u;
    if (tid == 0) g_total = 0u;
}

// ---------------- projector: 32-row chunk GEMM  dst = src @ W  ----------------
// srcMode 0: plain loads (X, pre-written).  srcMode 1: per-word sentinel poll
// (H0, written live by scan-0; in-place overwrite is safe: sole consumer is us,
// and the chunk is fully staged to LDS before any store).
static __device__ void proj_chunk(const float* __restrict__ W,
                                  const float* __restrict__ src, int srcMode,
                                  float* __restrict__ dst, uint32_t* flag, int t0,
                                  float* inT /* [DH][36] */, float* wt /* [32][516] */)
{
    const int tid = threadIdx.x;
    // stage input chunk transposed: inT[k][row]
    #pragma unroll
    for (int i = 0; i < 16; ++i) {
        int idx = tid + 1024 * i;            // 0..16383
        int row = idx >> 9;
        int col = idx & 511;
        float v;
        if (srcMode == 0) {
            v = src[(size_t)t0 * DH + idx];
        } else {
            const uint32_t* p = (const uint32_t*)src + (size_t)t0 * DH + idx;
            uint32_t u;
            while ((u = aload(p)) == SENT) __builtin_amdgcn_s_sleep(1);
            v = __uint_as_float(u);
        }
        inT[col * 36 + row] = v;
    }
    __syncthreads();

    const int rg = (tid >> 7) & 7;   // row group: rows 4rg..4rg+3
    const int cg = tid & 127;        // col group: cols 4cg..4cg+3
    float acc[4][4] = {{0.f}};

    for (int kt = 0; kt < 16; ++kt) {
        const int k0 = kt * 32;
        #pragma unroll
        for (int i = 0; i < 4; ++i) {                  // stage 32x512 W tile
            int f4 = tid + 1024 * i;                   // 0..4095 float4s
            int wr = f4 >> 7;
            int wc = (f4 & 127) << 2;
            *(float4*)&wt[wr * 516 + wc] =
                *(const float4*)&W[(size_t)(k0 + wr) * DH + wc];
        }
        __syncthreads();
        #pragma unroll 8
        for (int kk = 0; kk < 32; ++kk) {
            float4 a = *(const float4*)&inT[(k0 + kk) * 36 + (rg << 2)];
            float4 w = *(const float4*)&wt[kk * 516 + (cg << 2)];
            acc[0][0] += a.x * w.x; acc[0][1] += a.x * w.y; acc[0][2] += a.x * w.z; acc[0][3] += a.x * w.w;
            acc[1][0] += a.y * w.x; acc[1][1] += a.y * w.y; acc[1][2] += a.y * w.z; acc[1][3] += a.y * w.w;
            acc[2][0] += a.z * w.x; acc[2][1] += a.z * w.y; acc[2][2] += a.z * w.z; acc[2][3] += a.z * w.w;
            acc[3][0] += a.w * w.x; acc[3][1] += a.w * w.y; acc[3][2] += a.w * w.z; acc[3][3] += a.w * w.w;
        }
        __syncthreads();
    }
    #pragma unroll
    for (int i = 0; i < 4; ++i)
        #pragma unroll
        for (int j = 0; j < 4; ++j)
            astore((uint32_t*)&dst[(size_t)(t0 + (rg << 2) + i) * DH + (cg << 2) + j],
                   __float_as_uint(acc[i][j]));
    __threadfence();
    __syncthreads();
    if (tid == 0)
        __hip_atomic_store(flag, 1u, __ATOMIC_RELEASE, __HIP_MEMORY_SCOPE_AGENT);
}

// ---------------- fused persistent kernel ----------------
// grid = 64 x 1024, all blocks co-resident (already required by the flag
// protocols).  Roles from HW placement: each block reads its physical XCD via
// __builtin_amdgcn_s_getreg(HW_REG_XCC_ID=20) and registers; the first 8
// registrants on the lowest XCD with >=8 blocks (pigeonhole: must exist)
// become scan blocks (role 0..7: layer=role>>2, slice=role&3) — co-resident
// on ONE XCD by construction, so the h-ring runs on that XCD's L2 via sc0.
// Every poll has a bounded-retry escape to the agent-scope mirror ring, so a
// wrong placement/semantics assumption degrades to baseline speed, never hangs.
__global__ __launch_bounds__(1024, 1)
void fused(const float* __restrict__ X,
           const float* __restrict__ Wx0, const float* __restrict__ Wh0,
           const float* __restrict__ bh0, const float* __restrict__ h00,
           const float* __restrict__ Wx1, const float* __restrict__ Wh1,
           const float* __restrict__ bh1, const float* __restrict__ h01,
           float* H0r, float* H1r)
{
    __shared__ __align__(16) float s_hbuf[DH];
    __shared__ float s_part[8][128];
    __shared__ __align__(16) float s_inT[DH * 36];    // 73728 B
    __shared__ __align__(16) float s_wt[32 * 516];    // 66048 B
    __shared__ int s_role;
    __shared__ int s_fast;    // sticky: 1 = poll fast ring, 0 = mirror only

    const int bIdx = blockIdx.x;
    const int tid = threadIdx.x;

    // ---- placement-derived role assignment (tid 0) ----
    if (tid == 0) {
        // hwreg imm encoding: size-1=31 @ [15:11] | offset=0 @ [10:6] | id=20
        uint32_t xcd = ((uint32_t)__builtin_amdgcn_s_getreg((31 << 11) | 20)) & 7u;
        uint32_t slot = __hip_atomic_fetch_add(&g_cnt[xcd], 1u, __ATOMIC_RELAXED,
                                               __HIP_MEMORY_SCOPE_AGENT);
        astore(&g_members[xcd][slot & 63u], (uint32_t)bIdx);
        __hip_atomic_fetch_add(&g_total, 1u, __ATOMIC_RELEASE,
                               __HIP_MEMORY_SCOPE_AGENT);
        while (__hip_atomic_load(&g_total, __ATOMIC_ACQUIRE,
                                 __HIP_MEMORY_SCOPE_AGENT) < 64u)
            __builtin_amdgcn_s_sleep(2);
        uint32_t cnt[8];
        for (int x = 0; x < 8; ++x) cnt[x] = aload(&g_cnt[x]);
        int star = 0;
        for (int x = 0; x < 8; ++x) { if (cnt[x] >= 8u) { star = x; break; } }
        int role = -1;
        for (int s = 0; s < 8; ++s)
            if (aload(&g_members[star][s]) == (uint32_t)bIdx) role = s;
        if (role < 0) {
            int pi = 0;
            for (int x = 0; x < 8; ++x) {
                const uint32_t cx = cnt[x] > 64u ? 64u : cnt[x];
                for (uint32_t s = 0; s < cx; ++s) {
                    if (x == star && s < 8u) continue;
                    if (role < 0 &&
                        aload(&g_members[x][s]) == (uint32_t)bIdx) role = 8 + pi;
                    ++pi;
                }
            }
        }
        s_role = role;
        s_fast = 1;
    }
    __syncthreads();
    const int role = s_role;

    if (role >= 0 && role < 8) {
        // ================= scan role =================
        const int L = role >> 2;
        const int b = role & 3;           // slice 0..3, owns cols [128b,128b+128)
        const int c = tid >> 7;           // input chunk 0..7 (64 inputs)
        const int o = tid & 127;
        const int og = (b << 7) + o;

        const float* Wh  = L ? Wh1 : Wh0;
        const float* bhv = L ? bh1 : bh0;
        const float* h0v = L ? h01 : h00;
        float* Hful      = L ? H1r : H0r;
        const float* Xp  = L ? H0r : H1r;   // Xp1 overlays H0, Xp0 overlays H1
        uint32_t* ringF        = &g_ringF[L][0][0];
        uint32_t* ringM        = &g_ringM[L][0][0];
        uint32_t* flagXp       = &g_flagXp[L][0];

        float wh[64];
        #pragma unroll
        for (int j = 0; j < 64; ++j)
            wh[j] = Wh[(size_t)((c << 6) + j) * DH + og];
        const float bias = bhv[og];

        // pollers: 384 threads outside the self range, one remote col each
        const int ptid = (tid + 1024 - ((b << 8) + 256)) & 1023;
        const bool isPoll = ptid < 384;
        const int pcol = (ptid < (b << 7)) ? ptid : ptid + 128;
        const bool isSelf = (c >> 1) == b;
        const bool isRed = tid < 128;     // reducer threads, o == tid

        if (tid < DH) s_hbuf[tid] = h0v[tid];

        float xp_next = 0.f;
        int curCh = -1;
        if (isRed) {
            while (__hip_atomic_load(&flagXp[0], __ATOMIC_ACQUIRE,
                                     __HIP_MEMORY_SCOPE_AGENT) != 1u)
                __builtin_amdgcn_s_sleep(1);
            curCh = 0;
            xp_next = aloadf(&Xp[og]);
        }
        __syncthreads();

        for (int t = 0; t < TT; ++t) {
            if (t > 0 && isPoll) {
                const uint32_t par = (uint32_t)((t - 1) >> 4) & 1u;
                const int idx = (((t - 1) & 15) << 9) + pcol;
                uint32_t v;
                bool got = false;
                if (s_fast) {             // fast path: same-XCD L2 polling
                    for (int it = 0; it < 64; ++it) {
                        v = l2load(&ringF[idx]);
                        if ((v >> 31) == par) { got = true; break; }
                    }
                    if (!got) s_fast = 0; // sticky demote (benign LDS race)
                }
                if (!got) {               // proven agent-scope mirror path
                    do { v = aload(&ringM[idx]); } while ((v >> 31) != par);
                }
                s_hbuf[pcol] = __uint_as_float(v & 0x7fffffffu);
            }
            float acc = 0.f;
            if (isSelf | (t == 0)) {       // phase 1: overlaps the round trip
                const float4* h4 = (const float4*)&s_hbuf[c << 6];
                #pragma unroll
                for (int j4 = 0; j4 < 16; ++j4) {
                    float4 hv = h4[j4];
                    acc += wh[4*j4+0]*hv.x + wh[4*j4+1]*hv.y
                         + wh[4*j4+2]*hv.z + wh[4*j4+3]*hv.w;
                }
                s_part[c][o] = acc;
            }
            BARRIER_LDS();                 // remote h staged
            if (!(isSelf | (t == 0))) {    // phase 2: remote-dependent FMAs
                const float4* h4 = (const float4*)&s_hbuf[c << 6];
                #pragma unroll
                for (int j4 = 0; j4 < 16; ++j4) {
                    float4 hv = h4[j4];
                    acc += wh[4*j4+0]*hv.x + wh[4*j4+1]*hv.y
                         + wh[4*j4+2]*hv.z + wh[4*j4+3]*hv.w;
                }
                s_part[c][o] = acc;
            }
            BARRIER_LDS();                 // partials ready
            if (isRed) {
                float v = bias + xp_next;
                #pragma unroll
                for (int cc = 0; cc < 8; ++cc) v += s_part[cc][o];
                v = fmaxf(v, 0.f);
                const uint32_t hb = __float_as_uint(v);
                const uint32_t tag = hb | (((uint32_t)(t >> 4) & 1u) << 31);
                const int ridx = ((t & 15) << 9) + og;
                // fast ring first (consumers likely on it), then mirror
                l2store(&ringF[ridx], tag);
                astore(&ringM[ridx], tag);
                astore((uint32_t*)Hful + (size_t)t * DH + og, hb);
                s_hbuf[og] = v;
                if (t + 1 < TT) {          // prefetch next xp (off critical path)
                    const int ch = (t + 1) >> 5;
                    if (ch != curCh) {
                        while (__hip_atomic_load(&flagXp[ch], __ATOMIC_ACQUIRE,
                                                 __HIP_MEMORY_SCOPE_AGENT) != 1u) {}
                        curCh = ch;
                    }
                    xp_next = aloadf(&Xp[(size_t)(t + 1) * DH + og]);
                }
            }
            BARRIER_LDS();                 // hbuf self-slice ready for next step
        }
    } else {
        // ================= projector role =================
        const int pi = role - 8;                         // 0..55
        for (int cc = pi; cc < NCHUNK; cc += NPROJ) {
            proj_chunk(Wx0, X,   0, H1r /*Xp0*/, &g_flagXp[0][cc], cc * CROWS, s_inT, s_wt);
            proj_chunk(Wx1, H0r, 1, H0r /*Xp1*/, &g_flagXp[1][cc], cc * CROWS, s_inT, s_wt);
        }
    }
}

// out[t][k] = dot(H1[t], W_log[k]) + b_log[k].  Block = 8 timesteps x 128 k.
__global__ __launch_bounds__(128, 1)
void logits_kernel(const float* __restrict__ H1, const float* __restrict__ Wl,
                   const float* __restrict__ bl, float* __restrict__ out)
{
    const int t0 = blockIdx.x * 8;
    const int k = threadIdx.x;

    __shared__ __align__(16) float hs[8 * DH];
    for (int idx = k; idx < 8 * DH / 4; idx += 128)
        ((float4*)hs)[idx] = ((const float4*)&H1[(size_t)t0 * DH])[idx];
    __syncthreads();

    float acc[8];
    const float bk = bl[k];
    #pragma unroll
    for (int r = 0; r < 8; ++r) acc[r] = bk;

    const float4* w4 = (const float4*)&Wl[(size_t)k * DH];
    for (int j = 0; j < DH / 4; ++j) {
        float4 w = w4[j];
        #pragma unroll
        for (int r = 0; r < 8; ++r) {
            float4 h = ((const float4*)&hs[r * DH])[j];
            acc[r] += w.x * h.x + w.y * h.y + w.z * h.z + w.w * h.w;
        }
    }
    #pragma unroll
    for (int r = 0; r < 8; ++r) out[(size_t)(t0 + r) * KK + k] = acc[r];
}

extern "C" void kernel_launch(void* const* d_in, const int* in_sizes, int n_in,
                              void* d_out, int out_size, void* d_ws, size_t ws_size,
                              hipStream_t stream)
{
    const float* X   = (const float*)d_in[0];
    const float* Wx0 = (const float*)d_in[1];
    const float* Wh0 = (const float*)d_in[2];
    const float* bh0 = (const float*)d_in[3];
    const float* h00 = (const float*)d_in[4];
    const float* Wx1 = (const float*)d_in[5];
    const float* Wh1 = (const float*)d_in[6];
    const float* bh1 = (const float*)d_in[7];
    const float* h01 = (const float*)d_in[8];
    const float* Wl  = (const float*)d_in[9];
    const float* bl  = (const float*)d_in[10];
    float* out = (float*)d_out;

    float* H0r = (float*)d_ws;                  // H0, later overlaid by Xp1
    float* H1r = H0r + (size_t)TT * DH;         // Xp0 first, then H1

    // H0 region must start at sentinel (harness poisons d_ws; this is defensive)
    hipMemsetAsync(d_ws, 0xAA, (size_t)TT * DH * sizeof(float), stream);
    hipLaunchKernelGGL(init_kernel, dim3(1), dim3(1024), 0, stream);
    hipLaunchKernelGGL(fused, dim3(64), dim3(1024), 0, stream,
                       X, Wx0, Wh0, bh0, h00, Wx1, Wh1, bh1, h01, H0r, H1r);
    hipLaunchKernelGGL(logits_kernel, dim3(TT / 8), dim3(128), 0, stream,
                       H1r, Wl, bl, out);
}